// Round 7
// baseline (172.035 us; speedup 1.0000x reference)
//
#include <hip/hip_runtime.h>
#include <hip/hip_bf16.h>
#include <stdint.h>
#include <stddef.h>

// MMD via single signed 2N x 2N RBF gram, lower triangle only.
// Round 7: occupancy push. r6 (fp8, 64 KB LDS, 1 barrier/tile) sat at 2
// blocks/CU = 2 waves/SIMD -> latency-bound (MfmaUtil 32%, Occ 18%).
// This round: 16 KB k-half ping-pong (33 KB LDS total) + launch_bounds(256,3)
// + a_i row norms moved to LDS (saves 16 VGPRs) -> 3 blocks/CU, 3 waves/SIMD.
// Costs 2 barriers/tile; each staging phase has a full compute phase to land.

#define N_PTS   8192
#define DIM     256
#define TWO_N   16384
#define CSTRIDE 16

#define AS1 __attribute__((address_space(1)))
#define AS3 __attribute__((address_space(3)))

typedef __attribute__((ext_vector_type(4))) float f32x4;

// ---------------------------------------------------------------------------
// Prep: fp32 -> fp8 e4m3 (row-major) + c2-scaled fp32 row norms + zero output.
// n2[row] = c2 * |z_row|^2, c2 = -log2e/sigma (epilogue adds directly).
// ---------------------------------------------------------------------------
__global__ __launch_bounds__(256) void mmd_prep(const float* __restrict__ X,
                                                const float* __restrict__ Y,
                                                const int* __restrict__ sigmap,
                                                unsigned char* __restrict__ Zf8,
                                                float* __restrict__ n2,
                                                float* __restrict__ out) {
    if (blockIdx.x == 0 && threadIdx.x == 0) out[0] = 0.0f;

    const int wave = threadIdx.x >> 6;
    const int lane = threadIdx.x & 63;
    const int row  = blockIdx.x * 4 + wave;          // 0 .. TWO_N-1

    const float* src = (row < N_PTS) ? (X + (size_t)row * DIM)
                                     : (Y + (size_t)(row - N_PTS) * DIM);
    float4 v = ((const float4*)src)[lane];           // 64 lanes x 4 = 256

    float s = v.x * v.x + v.y * v.y + v.z * v.z + v.w * v.w;
#pragma unroll
    for (int off = 32; off; off >>= 1) s += __shfl_down(s, off, 64);
    if (lane == 0) {
        const float c2 = -1.4426950408889634f / (float)(*sigmap);
        n2[row] = c2 * s;
    }

    const int p01 = __builtin_amdgcn_cvt_pk_fp8_f32(v.x, v.y, 0, false);
    const int p23 = __builtin_amdgcn_cvt_pk_fp8_f32(v.z, v.w, 0, false);
    const unsigned int pk = ((unsigned)p01 & 0xffffu) | ((unsigned)p23 << 16);
    *(unsigned int*)(Zf8 + (size_t)row * DIM + (size_t)lane * 4) = pk;
}

// ---------------------------------------------------------------------------
// Main. grid = 128*16; br = 127 - (bid>>4) (heavy first), cc = bid & 15;
// empty blocks (cc > br) exit. 4 waves in 2x2; wave (wm,wn) owns 64x64 =
// 4x4 MFMA tiles of 16x16x32 fp8. A frags (full K=256, 64 VGPRs) stationary;
// B streams through two 16 KB k-half LDS buffers (ping-pong).
// ---------------------------------------------------------------------------
__global__ __launch_bounds__(256, 3) void mmd_main(const unsigned char* __restrict__ Zf8,
                                                   const float* __restrict__ n2,
                                                   const int* __restrict__ sigmap,
                                                   float* __restrict__ out) {
    __shared__ char smem_b[32768];   // 2 x 16 KB k-half B buffers, XOR swizzle
    __shared__ float n2rS[128];      // c2*|z|^2 for this block's 128 rows
    __shared__ float wsum[4];

    const int bid = (int)blockIdx.x;
    const int br  = 127 - (bid >> 4);
    const int cc  = bid & 15;
    if (cc > br) return;

    const int t    = threadIdx.x;
    const int wave = t >> 6;
    const int lane = t & 63;
    const int wm   = wave >> 1;
    const int wn   = wave & 1;
    const int g    = lane >> 4;      // k-quad
    const int ml   = lane & 15;
    const int rowBase = br * 128;

    const float m2 = 2.8853900817779268f / (float)(*sigmap);   // -2*c2

    // stage khalf0 of FIRST tile into buffer 0 (overlaps A-frag loads)
    {
        const int colBase0 = cc * 128;
#pragma unroll
        for (int i = 0; i < 4; ++i) {
            const int cidx = i * 256 + t;            // 0..1023 16B-chunks
            const int col  = cidx >> 3;              // col 0..127
            const int s    = cidx & 7;               // slot within 128B half-row
            const int gc   = s ^ (col & 7);          // XOR swizzle on source chunk
            const unsigned char* gp = Zf8 + (size_t)(colBase0 + col) * DIM + gc * 16;
            __builtin_amdgcn_global_load_lds((const AS1 void*)gp,
                                             (AS3 void*)(smem_b + (size_t)cidx * 16), 16, 0, 0);
        }
    }
    if (t < 128) n2rS[t] = n2[rowBase + t];          // row norms -> LDS

    // A fragments (full K, this wave's 64 rows): 64 VGPRs
    long af[4][8];
#pragma unroll
    for (int mt = 0; mt < 4; ++mt) {
        const unsigned char* rp =
            Zf8 + (size_t)(rowBase + wm * 64 + mt * 16 + ml) * DIM + g * 8;
#pragma unroll
        for (int kc = 0; kc < 8; ++kc)
            af[mt][kc] = *(const long*)(rp + kc * 32);
    }

    float block_acc = 0.0f;
    const int brX = (br < 64);

    for (int bc = cc; bc <= br; bc += CSTRIDE) {
        const int colBase = bc * 128;

        float b_j[4];
#pragma unroll
        for (int nt = 0; nt < 4; ++nt)
            b_j[nt] = n2[colBase + wn * 64 + nt * 16 + ml];

        f32x4 acc[4][4] = {};

        __syncthreads();             // khalf0 staged; buffer1 free

        // stage khalf1 of current tile (overlaps khalf0 compute)
#pragma unroll
        for (int i = 0; i < 4; ++i) {
            const int cidx = i * 256 + t;
            const int col  = cidx >> 3;
            const int s    = cidx & 7;
            const int gc   = s ^ (col & 7);
            const unsigned char* gp = Zf8 + (size_t)(colBase + col) * DIM + 128 + gc * 16;
            __builtin_amdgcn_global_load_lds((const AS1 void*)gp,
                                             (AS3 void*)(smem_b + 16384 + (size_t)cidx * 16), 16, 0, 0);
        }

        // compute khalf0: kc = 0..3
#pragma unroll
        for (int kc2 = 0; kc2 < 4; ++kc2) {
            const int jp   = kc2 * 2 + (g >> 1);     // 16B slot of granule kc2*4+g
            const int half = (g & 1) * 8;
            long bf[4];
#pragma unroll
            for (int nt = 0; nt < 4; ++nt) {
                const int col = wn * 64 + nt * 16 + ml;
                bf[nt] = *(const long*)(smem_b + (size_t)col * 128
                                            + (size_t)(jp ^ (col & 7)) * 16 + half);
            }
#pragma unroll
            for (int mt = 0; mt < 4; ++mt)
#pragma unroll
                for (int nt = 0; nt < 4; ++nt)
                    acc[mt][nt] = __builtin_amdgcn_mfma_f32_16x16x32_fp8_fp8(
                        af[mt][kc2], bf[nt], acc[mt][nt], 0, 0, 0);
        }

        __syncthreads();             // khalf1 staged; buffer0 free

        // stage khalf0 of NEXT tile (overlaps khalf1 compute + epilogue)
        if (bc + CSTRIDE <= br) {
            const int colBaseN = colBase + CSTRIDE * 128;
#pragma unroll
            for (int i = 0; i < 4; ++i) {
                const int cidx = i * 256 + t;
                const int col  = cidx >> 3;
                const int s    = cidx & 7;
                const int gc   = s ^ (col & 7);
                const unsigned char* gp = Zf8 + (size_t)(colBaseN + col) * DIM + gc * 16;
                __builtin_amdgcn_global_load_lds((const AS1 void*)gp,
                                                 (AS3 void*)(smem_b + (size_t)cidx * 16), 16, 0, 0);
            }
        }

        // compute khalf1: kc = 4..7
#pragma unroll
        for (int kc2 = 0; kc2 < 4; ++kc2) {
            const int jp   = kc2 * 2 + (g >> 1);
            const int half = (g & 1) * 8;
            long bf[4];
#pragma unroll
            for (int nt = 0; nt < 4; ++nt) {
                const int col = wn * 64 + nt * 16 + ml;
                bf[nt] = *(const long*)(smem_b + 16384 + (size_t)col * 128
                                            + (size_t)(jp ^ (col & 7)) * 16 + half);
            }
#pragma unroll
            for (int mt = 0; mt < 4; ++mt)
#pragma unroll
                for (int nt = 0; nt < 4; ++nt)
                    acc[mt][nt] = __builtin_amdgcn_mfma_f32_16x16x32_fp8_fp8(
                        af[mt][4 + kc2], bf[nt], acc[mt][nt], 0, 0, 0);
        }

        // epilogue: sum exp2(c2*n2i + c2*n2j + m2*dot), symmetry-weighted
        float tsum = 0.0f;
#pragma unroll
        for (int mt = 0; mt < 4; ++mt) {
            const f32x4 ar = *(const f32x4*)&n2rS[wm * 64 + mt * 16 + g * 4];
#pragma unroll
            for (int nt = 0; nt < 4; ++nt) {
                const float ab = b_j[nt];
#pragma unroll
                for (int rr = 0; rr < 4; ++rr)
                    tsum += __builtin_amdgcn_exp2f(
                        fmaf(acc[mt][nt][rr], m2, ar[rr] + ab));
            }
        }

        const float sgn = ((bc < 64) == brX) ? 1.0f : -1.0f;
        const float w   = (bc == br) ? sgn : 2.0f * sgn;
        block_acc = fmaf(w, tsum, block_acc);
    }

    // block reduction + single atomic
    float s = block_acc;
#pragma unroll
    for (int off = 32; off; off >>= 1) s += __shfl_down(s, off, 64);
    if (lane == 0) wsum[wave] = s;
    __syncthreads();
    if (t == 0)
        atomicAdd(out, (wsum[0] + wsum[1] + wsum[2] + wsum[3]) * (1.0f / 67108864.0f));
}

// ---------------------------------------------------------------------------
extern "C" void kernel_launch(void* const* d_in, const int* in_sizes, int n_in,
                              void* d_out, int out_size, void* d_ws, size_t ws_size,
                              hipStream_t stream) {
    const float* X      = (const float*)d_in[0];
    const float* Y      = (const float*)d_in[1];
    const int*   sigmap = (const int*)d_in[2];
    float*       out    = (float*)d_out;

    unsigned char* Zf8 = (unsigned char*)d_ws;                        // 4 MB
    float*         n2  = (float*)((char*)d_ws + (size_t)TWO_N * DIM);

    mmd_prep<<<TWO_N / 4, 256, 0, stream>>>(X, Y, sigmap, Zf8, n2, out);
    mmd_main<<<128 * CSTRIDE, 256, 0, stream>>>(Zf8, n2, sigmap, out);
}

// Round 8
// 146.640 us; speedup vs baseline: 1.1732x; 1.1732x over previous
//
#include <hip/hip_runtime.h>
#include <hip/hip_bf16.h>
#include <stdint.h>
#include <stddef.h>

// MMD via single signed 2N x 2N RBF gram, lower triangle only.
// Round 8: fp8 + 4x1 wave tiling (32x128/wave) + launch_bounds(256,3).
// r7 lesson: 2x2 tiling (af=64) + 170-reg cap => spill (65 MB scratch).
// 4x1 cuts af to 32 regs: core = af32 + acc64 + bf16 = 112, total ~160 <= 170
// -> no spill AND 3 blocks/CU (33 KB LDS k-half ping-pong) = 3 waves/SIMD.
// fp8 halves the 4x1 LDS-read penalty (~17us < 34us MFMA floor).

#define N_PTS   8192
#define DIM     256
#define TWO_N   16384
#define CSTRIDE 16

#define AS1 __attribute__((address_space(1)))
#define AS3 __attribute__((address_space(3)))

typedef __attribute__((ext_vector_type(4))) float f32x4;

// ---------------------------------------------------------------------------
// Prep: fp32 -> fp8 e4m3 (row-major) + c2-scaled fp32 row norms + zero output.
// n2[row] = c2 * |z_row|^2, c2 = -log2e/sigma (epilogue adds directly).
// ---------------------------------------------------------------------------
__global__ __launch_bounds__(256) void mmd_prep(const float* __restrict__ X,
                                                const float* __restrict__ Y,
                                                const int* __restrict__ sigmap,
                                                unsigned char* __restrict__ Zf8,
                                                float* __restrict__ n2,
                                                float* __restrict__ out) {
    if (blockIdx.x == 0 && threadIdx.x == 0) out[0] = 0.0f;

    const int wave = threadIdx.x >> 6;
    const int lane = threadIdx.x & 63;
    const int row  = blockIdx.x * 4 + wave;          // 0 .. TWO_N-1

    const float* src = (row < N_PTS) ? (X + (size_t)row * DIM)
                                     : (Y + (size_t)(row - N_PTS) * DIM);
    float4 v = ((const float4*)src)[lane];           // 64 lanes x 4 = 256

    float s = v.x * v.x + v.y * v.y + v.z * v.z + v.w * v.w;
#pragma unroll
    for (int off = 32; off; off >>= 1) s += __shfl_down(s, off, 64);
    if (lane == 0) {
        const float c2 = -1.4426950408889634f / (float)(*sigmap);
        n2[row] = c2 * s;
    }

    const int p01 = __builtin_amdgcn_cvt_pk_fp8_f32(v.x, v.y, 0, false);
    const int p23 = __builtin_amdgcn_cvt_pk_fp8_f32(v.z, v.w, 0, false);
    const unsigned int pk = ((unsigned)p01 & 0xffffu) | ((unsigned)p23 << 16);
    *(unsigned int*)(Zf8 + (size_t)row * DIM + (size_t)lane * 4) = pk;
}

// ---------------------------------------------------------------------------
// Main. grid = 128*16; br = 127 - (bid>>4) (heavy first), cc = bid & 15;
// empty blocks (cc > br) exit. 4 waves, 4x1: wave w owns rows [w*32, w*32+32)
// x all 128 cols = 2(mt) x 8(nt) MFMA tiles of 16x16x32 fp8.
// A frags (full K=256, 32 VGPRs) stationary; B streams through two 16 KB
// k-half LDS buffers (ping-pong, 2 barriers/tile).
// ---------------------------------------------------------------------------
__global__ __launch_bounds__(256, 3) void mmd_main(const unsigned char* __restrict__ Zf8,
                                                   const float* __restrict__ n2,
                                                   const int* __restrict__ sigmap,
                                                   float* __restrict__ out) {
    __shared__ char smem_b[32768];   // 2 x 16 KB k-half B buffers, XOR swizzle
    __shared__ float n2rS[128];      // c2*|z|^2 for this block's 128 rows
    __shared__ float wsum[4];

    const int bid = (int)blockIdx.x;
    const int br  = 127 - (bid >> 4);
    const int cc  = bid & 15;
    if (cc > br) return;

    const int t    = threadIdx.x;
    const int wave = t >> 6;
    const int lane = t & 63;
    const int g    = lane >> 4;      // k-quad
    const int ml   = lane & 15;
    const int rowBase = br * 128;

    const float m2 = 2.8853900817779268f / (float)(*sigmap);   // -2*c2

    // stage khalf0 of FIRST tile into buffer 0 (overlaps A-frag loads)
    {
        const int colBase0 = cc * 128;
#pragma unroll
        for (int i = 0; i < 4; ++i) {
            const int cidx = i * 256 + t;            // 0..1023 16B-chunks
            const int col  = cidx >> 3;              // col 0..127
            const int s    = cidx & 7;               // slot within 128B half-row
            const int gc   = s ^ (col & 7);          // XOR swizzle on source chunk
            const unsigned char* gp = Zf8 + (size_t)(colBase0 + col) * DIM + gc * 16;
            __builtin_amdgcn_global_load_lds((const AS1 void*)gp,
                                             (AS3 void*)(smem_b + (size_t)cidx * 16), 16, 0, 0);
        }
    }
    if (t < 128) n2rS[t] = n2[rowBase + t];          // row norms -> LDS

    // A fragments (full K, this wave's 32 rows): 32 VGPRs
    long af[2][8];
#pragma unroll
    for (int mt = 0; mt < 2; ++mt) {
        const unsigned char* rp =
            Zf8 + (size_t)(rowBase + wave * 32 + mt * 16 + ml) * DIM + g * 8;
#pragma unroll
        for (int kc = 0; kc < 8; ++kc)
            af[mt][kc] = *(const long*)(rp + kc * 32);
    }

    float block_acc = 0.0f;
    const int brX = (br < 64);

    for (int bc = cc; bc <= br; bc += CSTRIDE) {
        const int colBase = bc * 128;

        float b_j[8];
#pragma unroll
        for (int nt = 0; nt < 8; ++nt)
            b_j[nt] = n2[colBase + nt * 16 + ml];

        f32x4 acc[2][8] = {};

        __syncthreads();             // khalf0 staged; buffer1 free

        // stage khalf1 of current tile (overlaps khalf0 compute)
#pragma unroll
        for (int i = 0; i < 4; ++i) {
            const int cidx = i * 256 + t;
            const int col  = cidx >> 3;
            const int s    = cidx & 7;
            const int gc   = s ^ (col & 7);
            const unsigned char* gp = Zf8 + (size_t)(colBase + col) * DIM + 128 + gc * 16;
            __builtin_amdgcn_global_load_lds((const AS1 void*)gp,
                                             (AS3 void*)(smem_b + 16384 + (size_t)cidx * 16), 16, 0, 0);
        }

        // compute khalf0: kc = 0..3
#pragma unroll
        for (int kc2 = 0; kc2 < 4; ++kc2) {
            const int jp   = kc2 * 2 + (g >> 1);     // 16B slot of granule kc2*4+g
            const int half = (g & 1) * 8;
            long bf[8];
#pragma unroll
            for (int nt = 0; nt < 8; ++nt) {
                const int col = nt * 16 + ml;
                bf[nt] = *(const long*)(smem_b + (size_t)col * 128
                                            + (size_t)(jp ^ (col & 7)) * 16 + half);
            }
#pragma unroll
            for (int mt = 0; mt < 2; ++mt)
#pragma unroll
                for (int nt = 0; nt < 8; ++nt)
                    acc[mt][nt] = __builtin_amdgcn_mfma_f32_16x16x32_fp8_fp8(
                        af[mt][kc2], bf[nt], acc[mt][nt], 0, 0, 0);
        }

        __syncthreads();             // khalf1 staged; buffer0 free

        // stage khalf0 of NEXT tile (overlaps khalf1 compute + epilogue)
        if (bc + CSTRIDE <= br) {
            const int colBaseN = colBase + CSTRIDE * 128;
#pragma unroll
            for (int i = 0; i < 4; ++i) {
                const int cidx = i * 256 + t;
                const int col  = cidx >> 3;
                const int s    = cidx & 7;
                const int gc   = s ^ (col & 7);
                const unsigned char* gp = Zf8 + (size_t)(colBaseN + col) * DIM + gc * 16;
                __builtin_amdgcn_global_load_lds((const AS1 void*)gp,
                                                 (AS3 void*)(smem_b + (size_t)cidx * 16), 16, 0, 0);
            }
        }

        // compute khalf1: kc = 4..7
#pragma unroll
        for (int kc2 = 0; kc2 < 4; ++kc2) {
            const int jp   = kc2 * 2 + (g >> 1);
            const int half = (g & 1) * 8;
            long bf[8];
#pragma unroll
            for (int nt = 0; nt < 8; ++nt) {
                const int col = nt * 16 + ml;
                bf[nt] = *(const long*)(smem_b + 16384 + (size_t)col * 128
                                            + (size_t)(jp ^ (col & 7)) * 16 + half);
            }
#pragma unroll
            for (int mt = 0; mt < 2; ++mt)
#pragma unroll
                for (int nt = 0; nt < 8; ++nt)
                    acc[mt][nt] = __builtin_amdgcn_mfma_f32_16x16x32_fp8_fp8(
                        af[mt][4 + kc2], bf[nt], acc[mt][nt], 0, 0, 0);
        }

        // epilogue: sum exp2(c2*n2i + c2*n2j + m2*dot), symmetry-weighted
        float tsum = 0.0f;
#pragma unroll
        for (int mt = 0; mt < 2; ++mt) {
            const f32x4 ar = *(const f32x4*)&n2rS[wave * 32 + mt * 16 + g * 4];
#pragma unroll
            for (int nt = 0; nt < 8; ++nt) {
                const float ab = b_j[nt];
#pragma unroll
                for (int rr = 0; rr < 4; ++rr)
                    tsum += __builtin_amdgcn_exp2f(
                        fmaf(acc[mt][nt][rr], m2, ar[rr] + ab));
            }
        }

        const float sgn = ((bc < 64) == brX) ? 1.0f : -1.0f;
        const float w   = (bc == br) ? sgn : 2.0f * sgn;
        block_acc = fmaf(w, tsum, block_acc);
    }

    // block reduction + single atomic
    float s = block_acc;
#pragma unroll
    for (int off = 32; off; off >>= 1) s += __shfl_down(s, off, 64);
    if (lane == 0) wsum[wave] = s;
    __syncthreads();
    if (t == 0)
        atomicAdd(out, (wsum[0] + wsum[1] + wsum[2] + wsum[3]) * (1.0f / 67108864.0f));
}

// ---------------------------------------------------------------------------
extern "C" void kernel_launch(void* const* d_in, const int* in_sizes, int n_in,
                              void* d_out, int out_size, void* d_ws, size_t ws_size,
                              hipStream_t stream) {
    const float* X      = (const float*)d_in[0];
    const float* Y      = (const float*)d_in[1];
    const int*   sigmap = (const int*)d_in[2];
    float*       out    = (float*)d_out;

    unsigned char* Zf8 = (unsigned char*)d_ws;                        // 4 MB
    float*         n2  = (float*)((char*)d_ws + (size_t)TWO_N * DIM);

    mmd_prep<<<TWO_N / 4, 256, 0, stream>>>(X, Y, sigmap, Zf8, n2, out);
    mmd_main<<<128 * CSTRIDE, 256, 0, stream>>>(Zf8, n2, sigmap, out);
}

// Round 9
// 120.618 us; speedup vs baseline: 1.4263x; 1.2157x over previous
//
#include <hip/hip_runtime.h>
#include <hip/hip_bf16.h>
#include <stdint.h>
#include <stddef.h>

// MMD via single signed 2N x 2N RBF gram, lower triangle only.
// Round 9: r6 structure (fp8, 2x2 wave tiling, 64 KB full-tile double buffer,
// 1 barrier/tile, 2 blocks/CU) + MX-scaled MFMA 16x16x128 f8f6f4 with unit
// scales (0x7F = 2^0): 2.27x MFMA rate, 4x fewer MFMA instrs, same register
// footprint. Epilogue tsum split into 4 independent partial accumulators.

#define N_PTS   8192
#define DIM     256
#define TWO_N   16384
#define CSTRIDE 16

#define AS1 __attribute__((address_space(1)))
#define AS3 __attribute__((address_space(3)))

typedef __attribute__((ext_vector_type(4))) float f32x4;
typedef __attribute__((ext_vector_type(4))) int   i32x4;
typedef __attribute__((ext_vector_type(8))) int   i32x8;

// ---------------------------------------------------------------------------
// Prep: fp32 -> fp8 e4m3 (row-major) + c2-scaled fp32 row norms + zero output.
// n2[row] = c2 * |z_row|^2, c2 = -log2e/sigma (epilogue adds directly).
// ---------------------------------------------------------------------------
__global__ __launch_bounds__(256) void mmd_prep(const float* __restrict__ X,
                                                const float* __restrict__ Y,
                                                const int* __restrict__ sigmap,
                                                unsigned char* __restrict__ Zf8,
                                                float* __restrict__ n2,
                                                float* __restrict__ out) {
    if (blockIdx.x == 0 && threadIdx.x == 0) out[0] = 0.0f;

    const int wave = threadIdx.x >> 6;
    const int lane = threadIdx.x & 63;
    const int row  = blockIdx.x * 4 + wave;          // 0 .. TWO_N-1

    const float* src = (row < N_PTS) ? (X + (size_t)row * DIM)
                                     : (Y + (size_t)(row - N_PTS) * DIM);
    float4 v = ((const float4*)src)[lane];           // 64 lanes x 4 = 256

    float s = v.x * v.x + v.y * v.y + v.z * v.z + v.w * v.w;
#pragma unroll
    for (int off = 32; off; off >>= 1) s += __shfl_down(s, off, 64);
    if (lane == 0) {
        const float c2 = -1.4426950408889634f / (float)(*sigmap);
        n2[row] = c2 * s;
    }

    const int p01 = __builtin_amdgcn_cvt_pk_fp8_f32(v.x, v.y, 0, false);
    const int p23 = __builtin_amdgcn_cvt_pk_fp8_f32(v.z, v.w, 0, false);
    const unsigned int pk = ((unsigned)p01 & 0xffffu) | ((unsigned)p23 << 16);
    *(unsigned int*)(Zf8 + (size_t)row * DIM + (size_t)lane * 4) = pk;
}

// ---------------------------------------------------------------------------
// Main. grid = 128*16; br = 127 - (bid>>4) (heavy first), cc = bid & 15;
// empty blocks (cc > br) exit. 4 waves in 2x2; wave (wm,wn) owns 64x64 =
// 4x4 MFMA tiles of 16x16x128 MX-fp8 (2 k-chunks of K=128 each).
// A frags (full K=256, 64 VGPRs) stationary; B tiles (32 KB) double-buffered.
// Operand layout (K=128): lane (g=lane>>4, ml=lane&15) holds row/col ml,
// k = [kc*128 + g*32, +32) -> 32 contiguous bytes = i32x8.
// ---------------------------------------------------------------------------
__global__ __launch_bounds__(256, 2) void mmd_main(const unsigned char* __restrict__ Zf8,
                                                   const float* __restrict__ n2,
                                                   const int* __restrict__ sigmap,
                                                   float* __restrict__ out) {
    __shared__ char smem_b[65536];   // 2 x 32 KB B-tile buffers, 16B-slot XOR swizzle
    __shared__ float wsum[4];

    const int bid = (int)blockIdx.x;
    const int br  = 127 - (bid >> 4);
    const int cc  = bid & 15;
    if (cc > br) return;

    const int t    = threadIdx.x;
    const int wave = t >> 6;
    const int lane = t & 63;
    const int wm   = wave >> 1;
    const int wn   = wave & 1;
    const int g    = lane >> 4;      // k-quad
    const int ml   = lane & 15;
    const int rowBase = br * 128;

    const float m2 = 2.8853900817779268f / (float)(*sigmap);   // -2*c2
    const int   SC = 0x7f7f7f7f;     // E8M0 unit scales (2^0) for all blocks

    // ---- stage B tile 0 into buffer 0 (overlaps A-frag loads below) ----
    {
        const int colBase0 = cc * 128;
#pragma unroll
        for (int i = 0; i < 8; ++i) {
            const int cidx = i * 256 + t;            // 0..2047 16B-chunks
            const int col  = cidx >> 4;              // col 0..127
            const int s    = cidx & 15;              // LDS slot
            const int gc   = s ^ (col & 15);         // XOR swizzle on source chunk
            const unsigned char* gp = Zf8 + (size_t)(colBase0 + col) * DIM + gc * 16;
            __builtin_amdgcn_global_load_lds((const AS1 void*)gp,
                                             (AS3 void*)(smem_b + (size_t)cidx * 16), 16, 0, 0);
        }
    }

    // ---- A fragments (full K, this wave's 64 rows): 64 VGPRs ----
    i32x8 af[4][2];
#pragma unroll
    for (int mt = 0; mt < 4; ++mt) {
        const unsigned char* rp =
            Zf8 + (size_t)(rowBase + wm * 64 + mt * 16 + ml) * DIM + g * 32;
#pragma unroll
        for (int kc = 0; kc < 2; ++kc) {
            union { i32x4 h[2]; i32x8 v; } u;
            u.h[0] = *(const i32x4*)(rp + kc * 128);
            u.h[1] = *(const i32x4*)(rp + kc * 128 + 16);
            af[mt][kc] = u.v;
        }
    }
    // row-norm coefficients (c2-scaled) for this lane's 16 C rows
    float a_i[4][4];
#pragma unroll
    for (int mt = 0; mt < 4; ++mt)
#pragma unroll
        for (int rr = 0; rr < 4; ++rr)
            a_i[mt][rr] = n2[rowBase + wm * 64 + mt * 16 + g * 4 + rr];

    float block_acc = 0.0f;
    const int brX = (br < 64);
    int cur = 0;

    for (int bc = cc; bc <= br; bc += CSTRIDE) {
        const int colBase = bc * 128;

        float b_j[4];
#pragma unroll
        for (int nt = 0; nt < 4; ++nt)
            b_j[nt] = n2[colBase + wn * 64 + nt * 16 + ml];

        f32x4 acc[4][4] = {};

        __syncthreads();             // current buffer staged; other buffer free

        // ---- stage NEXT tile into the other buffer (overlaps compute) ----
        if (bc + CSTRIDE <= br) {
            const int colBaseN = colBase + CSTRIDE * 128;
            char* dst = smem_b + (cur ^ 1) * 32768;
#pragma unroll
            for (int i = 0; i < 8; ++i) {
                const int cidx = i * 256 + t;
                const int col  = cidx >> 4;
                const int s    = cidx & 15;
                const int gc   = s ^ (col & 15);
                const unsigned char* gp = Zf8 + (size_t)(colBaseN + col) * DIM + gc * 16;
                __builtin_amdgcn_global_load_lds((const AS1 void*)gp,
                                                 (AS3 void*)(dst + (size_t)cidx * 16), 16, 0, 0);
            }
        }

        // ---- compute: 2 k-chunks of K=128 ----
        const char* buf = smem_b + cur * 32768;
#pragma unroll
        for (int kc = 0; kc < 2; ++kc) {
            const int j0 = kc * 8 + g * 2;           // first 16B chunk of lane's 32B
            i32x8 bf[4];
#pragma unroll
            for (int nt = 0; nt < 4; ++nt) {
                const int col = wn * 64 + nt * 16 + ml;
                const char* cb = buf + (size_t)col * 256;
                union { i32x4 h[2]; i32x8 v; } u;
                u.h[0] = *(const i32x4*)(cb + (size_t)((j0)     ^ ml) * 16);
                u.h[1] = *(const i32x4*)(cb + (size_t)((j0 + 1) ^ ml) * 16);
                bf[nt] = u.v;
            }
#pragma unroll
            for (int mt = 0; mt < 4; ++mt)
#pragma unroll
                for (int nt = 0; nt < 4; ++nt)
                    acc[mt][nt] = __builtin_amdgcn_mfma_scale_f32_16x16x128_f8f6f4(
                        af[mt][kc], bf[nt], acc[mt][nt],
                        0, 0,              // cbsz: fp8 A, blgp: fp8 B
                        0, SC,             // scale A: opsel 0, unit scales
                        0, SC);            // scale B: opsel 0, unit scales
        }

        // ---- epilogue: 4 independent partial sums (break add chain) ----
        float ts0 = 0.0f, ts1 = 0.0f, ts2 = 0.0f, ts3 = 0.0f;
#pragma unroll
        for (int mt = 0; mt < 4; ++mt)
#pragma unroll
            for (int nt = 0; nt < 4; ++nt) {
                const float ab = b_j[nt];
                ts0 += __builtin_amdgcn_exp2f(fmaf(acc[mt][nt][0], m2, a_i[mt][0] + ab));
                ts1 += __builtin_amdgcn_exp2f(fmaf(acc[mt][nt][1], m2, a_i[mt][1] + ab));
                ts2 += __builtin_amdgcn_exp2f(fmaf(acc[mt][nt][2], m2, a_i[mt][2] + ab));
                ts3 += __builtin_amdgcn_exp2f(fmaf(acc[mt][nt][3], m2, a_i[mt][3] + ab));
            }
        const float tsum = (ts0 + ts1) + (ts2 + ts3);

        const float sgn = ((bc < 64) == brX) ? 1.0f : -1.0f;
        const float w   = (bc == br) ? sgn : 2.0f * sgn;   // symmetry weight
        block_acc = fmaf(w, tsum, block_acc);
        cur ^= 1;
    }

    // ---- block reduction + single atomic ----
    float s = block_acc;
#pragma unroll
    for (int off = 32; off; off >>= 1) s += __shfl_down(s, off, 64);
    if (lane == 0) wsum[wave] = s;
    __syncthreads();
    if (t == 0)
        atomicAdd(out, (wsum[0] + wsum[1] + wsum[2] + wsum[3]) * (1.0f / 67108864.0f));
}

// ---------------------------------------------------------------------------
extern "C" void kernel_launch(void* const* d_in, const int* in_sizes, int n_in,
                              void* d_out, int out_size, void* d_ws, size_t ws_size,
                              hipStream_t stream) {
    const float* X      = (const float*)d_in[0];
    const float* Y      = (const float*)d_in[1];
    const int*   sigmap = (const int*)d_in[2];
    float*       out    = (float*)d_out;

    unsigned char* Zf8 = (unsigned char*)d_ws;                        // 4 MB
    float*         n2  = (float*)((char*)d_ws + (size_t)TWO_N * DIM);

    mmd_prep<<<TWO_N / 4, 256, 0, stream>>>(X, Y, sigmap, Zf8, n2, out);
    mmd_main<<<128 * CSTRIDE, 256, 0, stream>>>(Zf8, n2, sigmap, out);
}